// Round 1
// baseline (1866.759 us; speedup 1.0000x reference)
//
#include <hip/hip_runtime.h>

#define N_NODES 50000
#define N_EDGES 800000
#define D_FEAT  64

// --- layout-flag: 1 => edge_index buffer is int64 (little-endian), 0 => int32 ---
__device__ inline void detect_idx_layout(const int* idx, int* flag) {
    // indices are in [0, 50000); if stored as int64 LE, every odd 32-bit word is 0.
    int allzero = 1;
    #pragma unroll
    for (int i = 1; i < 129; i += 2) {
        if (idx[i] != 0) { allzero = 0; }
    }
    *flag = allzero;
}

__global__ void init_kernel(float* __restrict__ out, int* __restrict__ flag,
                            const int* __restrict__ idx) {
    const int n4 = (N_NODES * D_FEAT) / 4;   // 800000 float4 per output tensor
    int tid = blockIdx.x * blockDim.x + threadIdx.x;
    int stride = gridDim.x * blockDim.x;
    float4* o = (float4*)out;
    const float4 z = make_float4(0.f, 0.f, 0.f, 0.f);
    const float4 one = make_float4(1.f, 1.f, 1.f, 1.f);
    for (int i = tid; i < n4; i += stride) {
        o[i] = z;            // out_sum = 0
        o[n4 + i] = one;     // out_prod = 1
    }
    if (blockIdx.x == 0 && threadIdx.x == 0) {
        detect_idx_layout(idx, flag);
    }
}

__device__ inline void atomicMulF32(float* addr, float val) {
    unsigned int* ua = (unsigned int*)addr;
    unsigned int old = __hip_atomic_load(ua, __ATOMIC_RELAXED, __HIP_MEMORY_SCOPE_AGENT);
    while (true) {
        unsigned int assumed = old;
        unsigned int desired = __float_as_uint(__uint_as_float(assumed) * val);
        old = atomicCAS(ua, assumed, desired);
        if (old == assumed) break;
    }
}

// one thread per (edge, 4-feature chunk): 800000 * 16 = 12.8M threads
__global__ void scatter_kernel(const float* __restrict__ xs,
                               const float* __restrict__ xp,
                               const int* __restrict__ idx,
                               float* __restrict__ out,
                               const int* __restrict__ flag) {
    long tid = (long)blockIdx.x * blockDim.x + threadIdx.x;
    const long total = (long)N_EDGES * (D_FEAT / 4);
    if (tid >= total) return;
    int e = (int)(tid >> 4);
    int c = (int)(tid & 15);

    int src, dst;
    if (*flag) {   // int64 little-endian layout: low word at 2*k
        src = idx[2 * e];
        dst = idx[2 * (N_EDGES + e)];
    } else {       // int32 layout
        src = idx[e];
        dst = idx[N_EDGES + e];
    }

    const float4 s = ((const float4*)(xs + (long)src * D_FEAT))[c];
    const float4 p = ((const float4*)(xp + (long)src * D_FEAT))[c];

    float* os = out + (long)dst * D_FEAT + c * 4;
    float* op = out + (long)N_NODES * D_FEAT + (long)dst * D_FEAT + c * 4;

    atomicAdd(os + 0, s.x);
    atomicAdd(os + 1, s.y);
    atomicAdd(os + 2, s.z);
    atomicAdd(os + 3, s.w);

    atomicMulF32(op + 0, p.x);
    atomicMulF32(op + 1, p.y);
    atomicMulF32(op + 2, p.z);
    atomicMulF32(op + 3, p.w);
}

extern "C" void kernel_launch(void* const* d_in, const int* in_sizes, int n_in,
                              void* d_out, int out_size, void* d_ws, size_t ws_size,
                              hipStream_t stream) {
    const float* x_sum  = (const float*)d_in[0];
    const float* x_prod = (const float*)d_in[1];
    const int*   eidx   = (const int*)d_in[2];
    float* out = (float*)d_out;
    int* flag = (int*)d_ws;

    // init: 800000 float4 pairs; 1024 blocks x 256 threads grid-stride
    init_kernel<<<1024, 256, 0, stream>>>(out, flag, eidx);

    const long total = (long)N_EDGES * (D_FEAT / 4);   // 12.8M
    int block = 256;
    int grid = (int)((total + block - 1) / block);     // 50000
    scatter_kernel<<<grid, block, 0, stream>>>(x_sum, x_prod, eidx, out, flag);
}

// Round 2
// 342.154 us; speedup vs baseline: 5.4559x; 5.4559x over previous
//
#include <hip/hip_runtime.h>

#define N_NODES 50000
#define N_EDGES 800000
#define D_FEAT  64

// ---------- workspace layout (ints) ----------
// W[0]               : layout flag (1 = int64 LE indices, 0 = int32)
// W[64 .. ]          : counts[50000]
// then offs[50001], cursor[50000], ssrc[800000]
#define WS_FLAG    0
#define WS_COUNTS  64
#define WS_OFFS    (WS_COUNTS + N_NODES)
#define WS_CURSOR  (WS_OFFS + N_NODES + 1)
#define WS_SSRC    (WS_CURSOR + N_NODES)
#define WS_INTS    (WS_SSRC + N_EDGES)

__device__ inline void detect_idx_layout(const int* idx, int* flag) {
    // indices < 50000: if stored as int64 LE, every odd 32-bit word is 0.
    int allzero = 1;
    #pragma unroll
    for (int i = 1; i < 129; i += 2) {
        if (idx[i] != 0) allzero = 0;
    }
    *flag = allzero;
}

// K0: init outputs (sum=0, prod=1), zero histogram, detect layout
__global__ void init_kernel(float* __restrict__ out, int* __restrict__ W,
                            const int* __restrict__ idx) {
    const int n4 = (N_NODES * D_FEAT) / 4;   // 800000 float4 per tensor
    int tid = blockIdx.x * blockDim.x + threadIdx.x;
    int stride = gridDim.x * blockDim.x;
    float4* o = (float4*)out;
    const float4 z = make_float4(0.f, 0.f, 0.f, 0.f);
    const float4 one = make_float4(1.f, 1.f, 1.f, 1.f);
    for (int i = tid; i < n4; i += stride) {
        o[i] = z;
        o[n4 + i] = one;
    }
    for (int i = tid; i < N_NODES; i += stride) W[WS_COUNTS + i] = 0;
    if (blockIdx.x == 0 && threadIdx.x == 0) detect_idx_layout(idx, W + WS_FLAG);
}

// K1: histogram of dst
__global__ void hist_kernel(const int* __restrict__ idx, int* __restrict__ W) {
    int e = blockIdx.x * blockDim.x + threadIdx.x;
    if (e >= N_EDGES) return;
    int dst = W[WS_FLAG] ? idx[2 * (N_EDGES + e)] : idx[N_EDGES + e];
    atomicAdd(&W[WS_COUNTS + dst], 1);
}

// K2: single-block exclusive scan of counts -> offs + cursor
__global__ void scan_kernel(int* __restrict__ W) {
    __shared__ int part[1024];
    const int CH = 49;  // 1024*49 = 50176 >= 50000
    int t = threadIdx.x;
    int base = t * CH;
    int local = 0;
    for (int i = 0; i < CH; ++i) {
        int j = base + i;
        if (j < N_NODES) local += W[WS_COUNTS + j];
    }
    part[t] = local;
    __syncthreads();
    for (int off = 1; off < 1024; off <<= 1) {
        int v = (t >= off) ? part[t - off] : 0;
        __syncthreads();
        part[t] += v;
        __syncthreads();
    }
    int prefix = (t == 0) ? 0 : part[t - 1];
    for (int i = 0; i < CH; ++i) {
        int j = base + i;
        if (j < N_NODES) {
            W[WS_OFFS + j] = prefix;
            W[WS_CURSOR + j] = prefix;
            prefix += W[WS_COUNTS + j];
        }
    }
    if (t == 1023) W[WS_OFFS + N_NODES] = part[1023];
}

// K3: scatter src into dst-sorted order
__global__ void scatter_sort(const int* __restrict__ idx, int* __restrict__ W) {
    int e = blockIdx.x * blockDim.x + threadIdx.x;
    if (e >= N_EDGES) return;
    int src, dst;
    if (W[WS_FLAG]) { src = idx[2 * e]; dst = idx[2 * (N_EDGES + e)]; }
    else            { src = idx[e];     dst = idx[N_EDGES + e]; }
    int pos = atomicAdd(&W[WS_CURSOR + dst], 1);
    W[WS_SSRC + pos] = src;
}

// K4: one wave per node; lane = feature. Register accumulation, single write.
__global__ __launch_bounds__(256) void gather_reduce(const float* __restrict__ xs,
                                                     const float* __restrict__ xp,
                                                     const int* __restrict__ W,
                                                     float* __restrict__ out) {
    int wave = (int)((blockIdx.x * blockDim.x + threadIdx.x) >> 6);
    int lane = threadIdx.x & 63;
    if (wave >= N_NODES) return;
    int beg = W[WS_OFFS + wave];
    int end = W[WS_OFFS + wave + 1];
    const int* ssrc = W + WS_SSRC;

    float s0 = 0.f, s1 = 0.f, p0 = 1.f, p1 = 1.f;
    int i = beg;
    for (; i + 1 < end; i += 2) {
        int a = ssrc[i];
        int b = ssrc[i + 1];
        float va = xs[a * D_FEAT + lane];
        float vb = xs[b * D_FEAT + lane];
        float wa = xp[a * D_FEAT + lane];
        float wb = xp[b * D_FEAT + lane];
        s0 += va; s1 += vb;
        p0 *= wa; p1 *= wb;
    }
    if (i < end) {
        int a = ssrc[i];
        s0 += xs[a * D_FEAT + lane];
        p0 *= xp[a * D_FEAT + lane];
    }
    out[(long)wave * D_FEAT + lane] = s0 + s1;
    out[(long)N_NODES * D_FEAT + (long)wave * D_FEAT + lane] = p0 * p1;
}

// ---------------- fallback (atomic) path, used only if ws is too small ----------------
__device__ inline void atomicMulF32(float* addr, float val) {
    unsigned int* ua = (unsigned int*)addr;
    unsigned int old = __hip_atomic_load(ua, __ATOMIC_RELAXED, __HIP_MEMORY_SCOPE_AGENT);
    while (true) {
        unsigned int assumed = old;
        unsigned int desired = __float_as_uint(__uint_as_float(assumed) * val);
        old = atomicCAS(ua, assumed, desired);
        if (old == assumed) break;
    }
}

__global__ void fb_init(float* __restrict__ out, int* __restrict__ flag,
                        const int* __restrict__ idx) {
    const int n4 = (N_NODES * D_FEAT) / 4;
    int tid = blockIdx.x * blockDim.x + threadIdx.x;
    int stride = gridDim.x * blockDim.x;
    float4* o = (float4*)out;
    const float4 z = make_float4(0.f, 0.f, 0.f, 0.f);
    const float4 one = make_float4(1.f, 1.f, 1.f, 1.f);
    for (int i = tid; i < n4; i += stride) { o[i] = z; o[n4 + i] = one; }
    if (blockIdx.x == 0 && threadIdx.x == 0) detect_idx_layout(idx, flag);
}

__global__ void fb_scatter(const float* __restrict__ xs, const float* __restrict__ xp,
                           const int* __restrict__ idx, float* __restrict__ out,
                           const int* __restrict__ flag) {
    long tid = (long)blockIdx.x * blockDim.x + threadIdx.x;
    const long total = (long)N_EDGES * (D_FEAT / 4);
    if (tid >= total) return;
    int e = (int)(tid >> 4);
    int c = (int)(tid & 15);
    int src, dst;
    if (*flag) { src = idx[2 * e]; dst = idx[2 * (N_EDGES + e)]; }
    else       { src = idx[e];     dst = idx[N_EDGES + e]; }
    const float4 s = ((const float4*)(xs + (long)src * D_FEAT))[c];
    const float4 p = ((const float4*)(xp + (long)src * D_FEAT))[c];
    float* os = out + (long)dst * D_FEAT + c * 4;
    float* op = out + (long)N_NODES * D_FEAT + (long)dst * D_FEAT + c * 4;
    atomicAdd(os + 0, s.x); atomicAdd(os + 1, s.y);
    atomicAdd(os + 2, s.z); atomicAdd(os + 3, s.w);
    atomicMulF32(op + 0, p.x); atomicMulF32(op + 1, p.y);
    atomicMulF32(op + 2, p.z); atomicMulF32(op + 3, p.w);
}

extern "C" void kernel_launch(void* const* d_in, const int* in_sizes, int n_in,
                              void* d_out, int out_size, void* d_ws, size_t ws_size,
                              hipStream_t stream) {
    const float* x_sum  = (const float*)d_in[0];
    const float* x_prod = (const float*)d_in[1];
    const int*   eidx   = (const int*)d_in[2];
    float* out = (float*)d_out;
    int* W = (int*)d_ws;

    if (ws_size < (size_t)WS_INTS * sizeof(int)) {
        // fallback: atomic path (correct but slow)
        fb_init<<<1024, 256, 0, stream>>>(out, W, eidx);
        const long total = (long)N_EDGES * (D_FEAT / 4);
        int grid = (int)((total + 255) / 256);
        fb_scatter<<<grid, 256, 0, stream>>>(x_sum, x_prod, eidx, out, W);
        return;
    }

    init_kernel<<<1024, 256, 0, stream>>>(out, W, eidx);
    hist_kernel<<<(N_EDGES + 255) / 256, 256, 0, stream>>>(eidx, W);
    scan_kernel<<<1, 1024, 0, stream>>>(W);
    scatter_sort<<<(N_EDGES + 255) / 256, 256, 0, stream>>>(eidx, W);
    // one wave per node; 4 waves/block -> 12500 blocks
    gather_reduce<<<(N_NODES + 3) / 4, 256, 0, stream>>>(x_sum, x_prod, W, out);
}

// Round 3
// 231.575 us; speedup vs baseline: 8.0611x; 1.4775x over previous
//
#include <hip/hip_runtime.h>

#define N_NODES 50000
#define N_EDGES 800000
#define D_FEAT  64
#define SCAN_B  196   // ceil(50000/256)

// ---------- workspace layout (ints) ----------
#define WS_FLAG    0
#define WS_COUNTS  64
#define WS_OFFS    (WS_COUNTS + N_NODES)
#define WS_CURSOR  (WS_OFFS + N_NODES + 1)
#define WS_SSRC    (WS_CURSOR + N_NODES)
#define WS_BSUM    (WS_SSRC + N_EDGES)
#define WS_INTS    (WS_BSUM + 256)

__device__ inline void detect_idx_layout(const int* idx, int* flag) {
    // indices < 50000: if stored as int64 LE, every odd 32-bit word is 0.
    int allzero = 1;
    #pragma unroll
    for (int i = 1; i < 129; i += 2) {
        if (idx[i] != 0) allzero = 0;
    }
    *flag = allzero;
}

// K0: zero histogram, detect layout, write offs[N] (compile-time constant total)
__global__ void init_kernel(int* __restrict__ W, const int* __restrict__ idx) {
    int tid = blockIdx.x * blockDim.x + threadIdx.x;
    int stride = gridDim.x * blockDim.x;
    for (int i = tid; i < N_NODES; i += stride) W[WS_COUNTS + i] = 0;
    if (tid == 0) {
        detect_idx_layout(idx, W + WS_FLAG);
        W[WS_OFFS + N_NODES] = N_EDGES;
    }
}

// K1: histogram of dst
__global__ void hist_kernel(const int* __restrict__ idx, int* __restrict__ W) {
    int e = blockIdx.x * blockDim.x + threadIdx.x;
    if (e >= N_EDGES) return;
    int dst = W[WS_FLAG] ? idx[2 * (N_EDGES + e)] : idx[N_EDGES + e];
    atomicAdd(&W[WS_COUNTS + dst], 1);
}

// K2a: per-block reduce of counts -> bsum[block]
__global__ __launch_bounds__(256) void scan_reduce(int* __restrict__ W) {
    int i = blockIdx.x * 256 + threadIdx.x;
    int v = (i < N_NODES) ? W[WS_COUNTS + i] : 0;
    // wave reduce (64 lanes)
    for (int off = 32; off > 0; off >>= 1) v += __shfl_down(v, off, 64);
    __shared__ int ws[4];
    int lane = threadIdx.x & 63;
    int wid = threadIdx.x >> 6;
    if (lane == 0) ws[wid] = v;
    __syncthreads();
    if (threadIdx.x == 0)
        W[WS_BSUM + blockIdx.x] = ws[0] + ws[1] + ws[2] + ws[3];
}

// K2b: single-block exclusive scan of bsum[SCAN_B]
__global__ __launch_bounds__(256) void scan_top(int* __restrict__ W) {
    __shared__ int part[256];
    int t = threadIdx.x;
    int v = (t < SCAN_B) ? W[WS_BSUM + t] : 0;
    part[t] = v;
    __syncthreads();
    for (int off = 1; off < 256; off <<= 1) {
        int u = (t >= off) ? part[t - off] : 0;
        __syncthreads();
        part[t] += u;
        __syncthreads();
    }
    if (t < SCAN_B) W[WS_BSUM + t] = part[t] - v;   // exclusive
}

// K2c: per-block LDS scan of counts + block prefix -> offs, cursor
__global__ __launch_bounds__(256) void scan_apply(int* __restrict__ W) {
    __shared__ int part[256];
    int t = threadIdx.x;
    int i = blockIdx.x * 256 + t;
    int c = (i < N_NODES) ? W[WS_COUNTS + i] : 0;
    part[t] = c;
    __syncthreads();
    for (int off = 1; off < 256; off <<= 1) {
        int u = (t >= off) ? part[t - off] : 0;
        __syncthreads();
        part[t] += u;
        __syncthreads();
    }
    int excl = part[t] - c + W[WS_BSUM + blockIdx.x];
    if (i < N_NODES) {
        W[WS_OFFS + i] = excl;
        W[WS_CURSOR + i] = excl;
    }
}

// K3: scatter src into dst-sorted order
__global__ void scatter_sort(const int* __restrict__ idx, int* __restrict__ W) {
    int e = blockIdx.x * blockDim.x + threadIdx.x;
    if (e >= N_EDGES) return;
    int src, dst;
    if (W[WS_FLAG]) { src = idx[2 * e]; dst = idx[2 * (N_EDGES + e)]; }
    else            { src = idx[e];     dst = idx[N_EDGES + e]; }
    int pos = atomicAdd(&W[WS_CURSOR + dst], 1);
    W[WS_SSRC + pos] = src;
}

// K4: one wave per node; lane = feature. Register accumulation, single write.
__global__ __launch_bounds__(256) void gather_reduce(const float* __restrict__ xs,
                                                     const float* __restrict__ xp,
                                                     const int* __restrict__ W,
                                                     float* __restrict__ out) {
    int wave = (int)((blockIdx.x * blockDim.x + threadIdx.x) >> 6);
    int lane = threadIdx.x & 63;
    if (wave >= N_NODES) return;
    int beg = W[WS_OFFS + wave];
    int end = W[WS_OFFS + wave + 1];
    const int* ssrc = W + WS_SSRC;

    float s0 = 0.f, s1 = 0.f, p0 = 1.f, p1 = 1.f;
    int i = beg;
    for (; i + 1 < end; i += 2) {
        int a = ssrc[i];
        int b = ssrc[i + 1];
        float va = xs[a * D_FEAT + lane];
        float vb = xs[b * D_FEAT + lane];
        float wa = xp[a * D_FEAT + lane];
        float wb = xp[b * D_FEAT + lane];
        s0 += va; s1 += vb;
        p0 *= wa; p1 *= wb;
    }
    if (i < end) {
        int a = ssrc[i];
        s0 += xs[a * D_FEAT + lane];
        p0 *= xp[a * D_FEAT + lane];
    }
    out[(long)wave * D_FEAT + lane] = s0 + s1;
    out[(long)N_NODES * D_FEAT + (long)wave * D_FEAT + lane] = p0 * p1;
}

// ---------------- fallback (atomic) path, used only if ws is too small ----------------
__device__ inline void atomicMulF32(float* addr, float val) {
    unsigned int* ua = (unsigned int*)addr;
    unsigned int old = __hip_atomic_load(ua, __ATOMIC_RELAXED, __HIP_MEMORY_SCOPE_AGENT);
    while (true) {
        unsigned int assumed = old;
        unsigned int desired = __float_as_uint(__uint_as_float(assumed) * val);
        old = atomicCAS(ua, assumed, desired);
        if (old == assumed) break;
    }
}

__global__ void fb_init(float* __restrict__ out, int* __restrict__ flag,
                        const int* __restrict__ idx) {
    const int n4 = (N_NODES * D_FEAT) / 4;
    int tid = blockIdx.x * blockDim.x + threadIdx.x;
    int stride = gridDim.x * blockDim.x;
    float4* o = (float4*)out;
    const float4 z = make_float4(0.f, 0.f, 0.f, 0.f);
    const float4 one = make_float4(1.f, 1.f, 1.f, 1.f);
    for (int i = tid; i < n4; i += stride) { o[i] = z; o[n4 + i] = one; }
    if (blockIdx.x == 0 && threadIdx.x == 0) detect_idx_layout(idx, flag);
}

__global__ void fb_scatter(const float* __restrict__ xs, const float* __restrict__ xp,
                           const int* __restrict__ idx, float* __restrict__ out,
                           const int* __restrict__ flag) {
    long tid = (long)blockIdx.x * blockDim.x + threadIdx.x;
    const long total = (long)N_EDGES * (D_FEAT / 4);
    if (tid >= total) return;
    int e = (int)(tid >> 4);
    int c = (int)(tid & 15);
    int src, dst;
    if (*flag) { src = idx[2 * e]; dst = idx[2 * (N_EDGES + e)]; }
    else       { src = idx[e];     dst = idx[N_EDGES + e]; }
    const float4 s = ((const float4*)(xs + (long)src * D_FEAT))[c];
    const float4 p = ((const float4*)(xp + (long)src * D_FEAT))[c];
    float* os = out + (long)dst * D_FEAT + c * 4;
    float* op = out + (long)N_NODES * D_FEAT + (long)dst * D_FEAT + c * 4;
    atomicAdd(os + 0, s.x); atomicAdd(os + 1, s.y);
    atomicAdd(os + 2, s.z); atomicAdd(os + 3, s.w);
    atomicMulF32(op + 0, p.x); atomicMulF32(op + 1, p.y);
    atomicMulF32(op + 2, p.z); atomicMulF32(op + 3, p.w);
}

extern "C" void kernel_launch(void* const* d_in, const int* in_sizes, int n_in,
                              void* d_out, int out_size, void* d_ws, size_t ws_size,
                              hipStream_t stream) {
    const float* x_sum  = (const float*)d_in[0];
    const float* x_prod = (const float*)d_in[1];
    const int*   eidx   = (const int*)d_in[2];
    float* out = (float*)d_out;
    int* W = (int*)d_ws;

    if (ws_size < (size_t)WS_INTS * sizeof(int)) {
        fb_init<<<1024, 256, 0, stream>>>(out, W, eidx);
        const long total = (long)N_EDGES * (D_FEAT / 4);
        int grid = (int)((total + 255) / 256);
        fb_scatter<<<grid, 256, 0, stream>>>(x_sum, x_prod, eidx, out, W);
        return;
    }

    init_kernel<<<64, 256, 0, stream>>>(W, eidx);
    hist_kernel<<<(N_EDGES + 255) / 256, 256, 0, stream>>>(eidx, W);
    scan_reduce<<<SCAN_B, 256, 0, stream>>>(W);
    scan_top<<<1, 256, 0, stream>>>(W);
    scan_apply<<<SCAN_B, 256, 0, stream>>>(W);
    scatter_sort<<<(N_EDGES + 255) / 256, 256, 0, stream>>>(eidx, W);
    gather_reduce<<<(N_NODES + 3) / 4, 256, 0, stream>>>(x_sum, x_prod, W, out);
}

// Round 4
// 219.060 us; speedup vs baseline: 8.5217x; 1.0571x over previous
//
#include <hip/hip_runtime.h>

#define N_NODES 50000
#define N_EDGES 800000
#define D_FEAT  64
#define SCAN_B  196   // ceil(50000/256)

// ---------- workspace layout (ints) ----------
#define WS_FLAG    0
#define WS_COUNTS  64
#define WS_OFFS    (WS_COUNTS + N_NODES)
#define WS_CURSOR  (WS_OFFS + N_NODES + 1)
#define WS_SSRC    (WS_CURSOR + N_NODES)
#define WS_BSUM    (WS_SSRC + N_EDGES)
#define WS_INTS    (WS_BSUM + 256)

__device__ inline void detect_idx_layout(const int* idx, int* flag) {
    // indices < 50000: if stored as int64 LE, every odd 32-bit word is 0.
    int allzero = 1;
    #pragma unroll
    for (int i = 1; i < 129; i += 2) {
        if (idx[i] != 0) allzero = 0;
    }
    *flag = allzero;
}

// K0: zero histogram, detect layout, write offs[N]
__global__ void init_kernel(int* __restrict__ W, const int* __restrict__ idx) {
    int tid = blockIdx.x * blockDim.x + threadIdx.x;
    int stride = gridDim.x * blockDim.x;
    for (int i = tid; i < N_NODES; i += stride) W[WS_COUNTS + i] = 0;
    if (tid == 0) {
        detect_idx_layout(idx, W + WS_FLAG);
        W[WS_OFFS + N_NODES] = N_EDGES;
    }
}

// K1: histogram of dst — 2 edges per thread, vector index loads
__global__ __launch_bounds__(256) void hist_kernel(const int* __restrict__ idx,
                                                   int* __restrict__ W) {
    int t = blockIdx.x * blockDim.x + threadIdx.x;
    if (t >= N_EDGES / 2) return;
    int d0, d1;
    if (W[WS_FLAG]) {
        int4 v = *(const int4*)&idx[2 * (N_EDGES + 2 * t)];
        d0 = v.x; d1 = v.z;
    } else {
        int2 v = *(const int2*)&idx[N_EDGES + 2 * t];
        d0 = v.x; d1 = v.y;
    }
    atomicAdd(&W[WS_COUNTS + d0], 1);
    atomicAdd(&W[WS_COUNTS + d1], 1);
}

// K2a: per-block reduce of counts -> bsum[block]
__global__ __launch_bounds__(256) void scan_reduce(int* __restrict__ W) {
    int i = blockIdx.x * 256 + threadIdx.x;
    int v = (i < N_NODES) ? W[WS_COUNTS + i] : 0;
    for (int off = 32; off > 0; off >>= 1) v += __shfl_down(v, off, 64);
    __shared__ int ws[4];
    int lane = threadIdx.x & 63;
    int wid = threadIdx.x >> 6;
    if (lane == 0) ws[wid] = v;
    __syncthreads();
    if (threadIdx.x == 0)
        W[WS_BSUM + blockIdx.x] = ws[0] + ws[1] + ws[2] + ws[3];
}

// K2b: fused top-scan + per-block scan of counts -> offs, cursor
__global__ __launch_bounds__(256) void scan_apply(int* __restrict__ W) {
    __shared__ int part[256];
    int t = threadIdx.x;

    // top-level: every block redundantly scans the 196 block sums
    part[t] = (t < SCAN_B) ? W[WS_BSUM + t] : 0;
    __syncthreads();
    for (int off = 1; off < 256; off <<= 1) {
        int u = (t >= off) ? part[t - off] : 0;
        __syncthreads();
        part[t] += u;
        __syncthreads();
    }
    int blockPrefix = (blockIdx.x == 0) ? 0 : part[blockIdx.x - 1];
    __syncthreads();

    // per-block scan of counts
    int i = blockIdx.x * 256 + t;
    int c = (i < N_NODES) ? W[WS_COUNTS + i] : 0;
    part[t] = c;
    __syncthreads();
    for (int off = 1; off < 256; off <<= 1) {
        int u = (t >= off) ? part[t - off] : 0;
        __syncthreads();
        part[t] += u;
        __syncthreads();
    }
    int excl = part[t] - c + blockPrefix;
    if (i < N_NODES) {
        W[WS_OFFS + i] = excl;
        W[WS_CURSOR + i] = excl;
    }
}

// K3: scatter src into dst-sorted order — 2 edges per thread
__global__ __launch_bounds__(256) void scatter_sort(const int* __restrict__ idx,
                                                    int* __restrict__ W) {
    int t = blockIdx.x * blockDim.x + threadIdx.x;
    if (t >= N_EDGES / 2) return;
    int s0, s1, d0, d1;
    if (W[WS_FLAG]) {
        int4 sv = *(const int4*)&idx[4 * t];
        int4 dv = *(const int4*)&idx[2 * (N_EDGES + 2 * t)];
        s0 = sv.x; s1 = sv.z; d0 = dv.x; d1 = dv.z;
    } else {
        int2 sv = *(const int2*)&idx[2 * t];
        int2 dv = *(const int2*)&idx[N_EDGES + 2 * t];
        s0 = sv.x; s1 = sv.y; d0 = dv.x; d1 = dv.y;
    }
    int p0 = atomicAdd(&W[WS_CURSOR + d0], 1);
    W[WS_SSRC + p0] = s0;
    int p1 = atomicAdd(&W[WS_CURSOR + d1], 1);
    W[WS_SSRC + p1] = s1;
}

// K4: one wave per node; lane = feature. 4-way unrolled register accumulation.
__global__ __launch_bounds__(256) void gather_reduce(const float* __restrict__ xs,
                                                     const float* __restrict__ xp,
                                                     const int* __restrict__ W,
                                                     float* __restrict__ out) {
    int wave = (int)((blockIdx.x * blockDim.x + threadIdx.x) >> 6);
    int lane = threadIdx.x & 63;
    if (wave >= N_NODES) return;
    int beg = W[WS_OFFS + wave];
    int end = W[WS_OFFS + wave + 1];
    const int* ssrc = W + WS_SSRC;

    float s0 = 0.f, s1 = 0.f, s2 = 0.f, s3 = 0.f;
    float p0 = 1.f, p1 = 1.f, p2 = 1.f, p3 = 1.f;
    int i = beg;
    for (; i + 3 < end; i += 4) {
        int a = ssrc[i], b = ssrc[i + 1], c = ssrc[i + 2], d = ssrc[i + 3];
        float va = xs[a * D_FEAT + lane];
        float vb = xs[b * D_FEAT + lane];
        float vc = xs[c * D_FEAT + lane];
        float vd = xs[d * D_FEAT + lane];
        float wa = xp[a * D_FEAT + lane];
        float wb = xp[b * D_FEAT + lane];
        float wc = xp[c * D_FEAT + lane];
        float wd = xp[d * D_FEAT + lane];
        s0 += va; s1 += vb; s2 += vc; s3 += vd;
        p0 *= wa; p1 *= wb; p2 *= wc; p3 *= wd;
    }
    for (; i < end; ++i) {
        int a = ssrc[i];
        s0 += xs[a * D_FEAT + lane];
        p0 *= xp[a * D_FEAT + lane];
    }
    out[(long)wave * D_FEAT + lane] = (s0 + s1) + (s2 + s3);
    out[(long)N_NODES * D_FEAT + (long)wave * D_FEAT + lane] = (p0 * p1) * (p2 * p3);
}

// ---------------- fallback (atomic) path, used only if ws is too small ----------------
__device__ inline void atomicMulF32(float* addr, float val) {
    unsigned int* ua = (unsigned int*)addr;
    unsigned int old = __hip_atomic_load(ua, __ATOMIC_RELAXED, __HIP_MEMORY_SCOPE_AGENT);
    while (true) {
        unsigned int assumed = old;
        unsigned int desired = __float_as_uint(__uint_as_float(assumed) * val);
        old = atomicCAS(ua, assumed, desired);
        if (old == assumed) break;
    }
}

__global__ void fb_init(float* __restrict__ out, int* __restrict__ flag,
                        const int* __restrict__ idx) {
    const int n4 = (N_NODES * D_FEAT) / 4;
    int tid = blockIdx.x * blockDim.x + threadIdx.x;
    int stride = gridDim.x * blockDim.x;
    float4* o = (float4*)out;
    const float4 z = make_float4(0.f, 0.f, 0.f, 0.f);
    const float4 one = make_float4(1.f, 1.f, 1.f, 1.f);
    for (int i = tid; i < n4; i += stride) { o[i] = z; o[n4 + i] = one; }
    if (blockIdx.x == 0 && threadIdx.x == 0) detect_idx_layout(idx, flag);
}

__global__ void fb_scatter(const float* __restrict__ xs, const float* __restrict__ xp,
                           const int* __restrict__ idx, float* __restrict__ out,
                           const int* __restrict__ flag) {
    long tid = (long)blockIdx.x * blockDim.x + threadIdx.x;
    const long total = (long)N_EDGES * (D_FEAT / 4);
    if (tid >= total) return;
    int e = (int)(tid >> 4);
    int c = (int)(tid & 15);
    int src, dst;
    if (*flag) { src = idx[2 * e]; dst = idx[2 * (N_EDGES + e)]; }
    else       { src = idx[e];     dst = idx[N_EDGES + e]; }
    const float4 s = ((const float4*)(xs + (long)src * D_FEAT))[c];
    const float4 p = ((const float4*)(xp + (long)src * D_FEAT))[c];
    float* os = out + (long)dst * D_FEAT + c * 4;
    float* op = out + (long)N_NODES * D_FEAT + (long)dst * D_FEAT + c * 4;
    atomicAdd(os + 0, s.x); atomicAdd(os + 1, s.y);
    atomicAdd(os + 2, s.z); atomicAdd(os + 3, s.w);
    atomicMulF32(op + 0, p.x); atomicMulF32(op + 1, p.y);
    atomicMulF32(op + 2, p.z); atomicMulF32(op + 3, p.w);
}

extern "C" void kernel_launch(void* const* d_in, const int* in_sizes, int n_in,
                              void* d_out, int out_size, void* d_ws, size_t ws_size,
                              hipStream_t stream) {
    const float* x_sum  = (const float*)d_in[0];
    const float* x_prod = (const float*)d_in[1];
    const int*   eidx   = (const int*)d_in[2];
    float* out = (float*)d_out;
    int* W = (int*)d_ws;

    if (ws_size < (size_t)WS_INTS * sizeof(int)) {
        fb_init<<<1024, 256, 0, stream>>>(out, W, eidx);
        const long total = (long)N_EDGES * (D_FEAT / 4);
        int grid = (int)((total + 255) / 256);
        fb_scatter<<<grid, 256, 0, stream>>>(x_sum, x_prod, eidx, out, W);
        return;
    }

    init_kernel<<<64, 256, 0, stream>>>(W, eidx);
    hist_kernel<<<(N_EDGES / 2 + 255) / 256, 256, 0, stream>>>(eidx, W);
    scan_reduce<<<SCAN_B, 256, 0, stream>>>(W);
    scan_apply<<<SCAN_B, 256, 0, stream>>>(W);
    scatter_sort<<<(N_EDGES / 2 + 255) / 256, 256, 0, stream>>>(eidx, W);
    gather_reduce<<<(N_NODES + 3) / 4, 256, 0, stream>>>(x_sum, x_prod, W, out);
}

// Round 5
// 206.337 us; speedup vs baseline: 9.0471x; 1.0617x over previous
//
#include <hip/hip_runtime.h>
#include <hip/hip_fp16.h>

#define N_NODES 50000
#define N_EDGES 800000
#define D_FEAT  64
#define SCAN_B  196   // ceil(50000/256)

// ---------- workspace layout ----------
#define WS_FLAG    0
#define WS_COUNTS  64
#define WS_OFFS    (WS_COUNTS + N_NODES)
#define WS_CURSOR  (WS_OFFS + N_NODES + 1)
#define WS_SSRC    (WS_CURSOR + N_NODES)
#define WS_BSUM    (WS_SSRC + N_EDGES)
#define WS_PACKED  (WS_BSUM + 256)            // __half2[N_NODES*D_FEAT], 4B each
#define WS_INTS    (WS_PACKED + N_NODES * D_FEAT)

__device__ inline void detect_idx_layout(const int* idx, int* flag) {
    // indices < 50000: if stored as int64 LE, every odd 32-bit word is 0.
    int allzero = 1;
    #pragma unroll
    for (int i = 1; i < 129; i += 2) {
        if (idx[i] != 0) allzero = 0;
    }
    *flag = allzero;
}

// K0: zero histogram, detect layout, cast+interleave feature tables to fp16
__global__ __launch_bounds__(256) void init_cast(int* __restrict__ W,
                                                 const int* __restrict__ idx,
                                                 const float* __restrict__ xs,
                                                 const float* __restrict__ xp) {
    int tid = blockIdx.x * blockDim.x + threadIdx.x;
    int stride = gridDim.x * blockDim.x;
    for (int i = tid; i < N_NODES; i += stride) W[WS_COUNTS + i] = 0;
    __half2* packed = (__half2*)(W + WS_PACKED);
    const int total = N_NODES * D_FEAT;
    for (int i = tid; i < total; i += stride)
        packed[i] = __floats2half2_rn(xs[i], xp[i]);
    if (tid == 0) {
        detect_idx_layout(idx, W + WS_FLAG);
        W[WS_OFFS + N_NODES] = N_EDGES;
    }
}

// K1: histogram of dst — 8 edges per thread, pipelined atomics
__global__ __launch_bounds__(256) void hist_kernel(const int* __restrict__ idx,
                                                   int* __restrict__ W) {
    int t = blockIdx.x * blockDim.x + threadIdx.x;
    if (t >= N_EDGES / 8) return;
    int e0 = 8 * t;
    int d[8];
    if (W[WS_FLAG]) {
        #pragma unroll
        for (int k = 0; k < 8; k += 2) {
            int4 v = *(const int4*)&idx[2 * (N_EDGES + e0 + k)];
            d[k] = v.x; d[k + 1] = v.z;
        }
    } else {
        #pragma unroll
        for (int k = 0; k < 8; k += 4) {
            int4 v = *(const int4*)&idx[N_EDGES + e0 + k];
            d[k] = v.x; d[k + 1] = v.y; d[k + 2] = v.z; d[k + 3] = v.w;
        }
    }
    #pragma unroll
    for (int k = 0; k < 8; ++k) atomicAdd(&W[WS_COUNTS + d[k]], 1);
}

// K2a: per-block reduce of counts -> bsum[block]
__global__ __launch_bounds__(256) void scan_reduce(int* __restrict__ W) {
    int i = blockIdx.x * 256 + threadIdx.x;
    int v = (i < N_NODES) ? W[WS_COUNTS + i] : 0;
    for (int off = 32; off > 0; off >>= 1) v += __shfl_down(v, off, 64);
    __shared__ int ws[4];
    int lane = threadIdx.x & 63;
    int wid = threadIdx.x >> 6;
    if (lane == 0) ws[wid] = v;
    __syncthreads();
    if (threadIdx.x == 0)
        W[WS_BSUM + blockIdx.x] = ws[0] + ws[1] + ws[2] + ws[3];
}

// K2b: fused top-scan + per-block scan of counts -> offs, cursor
__global__ __launch_bounds__(256) void scan_apply(int* __restrict__ W) {
    __shared__ int part[256];
    int t = threadIdx.x;

    part[t] = (t < SCAN_B) ? W[WS_BSUM + t] : 0;
    __syncthreads();
    for (int off = 1; off < 256; off <<= 1) {
        int u = (t >= off) ? part[t - off] : 0;
        __syncthreads();
        part[t] += u;
        __syncthreads();
    }
    int blockPrefix = (blockIdx.x == 0) ? 0 : part[blockIdx.x - 1];
    __syncthreads();

    int i = blockIdx.x * 256 + t;
    int c = (i < N_NODES) ? W[WS_COUNTS + i] : 0;
    part[t] = c;
    __syncthreads();
    for (int off = 1; off < 256; off <<= 1) {
        int u = (t >= off) ? part[t - off] : 0;
        __syncthreads();
        part[t] += u;
        __syncthreads();
    }
    int excl = part[t] - c + blockPrefix;
    if (i < N_NODES) {
        W[WS_OFFS + i] = excl;
        W[WS_CURSOR + i] = excl;
    }
}

// K3: scatter src into dst-sorted order — 8 edges per thread, pipelined atomics
__global__ __launch_bounds__(256) void scatter_sort(const int* __restrict__ idx,
                                                    int* __restrict__ W) {
    int t = blockIdx.x * blockDim.x + threadIdx.x;
    if (t >= N_EDGES / 8) return;
    int e0 = 8 * t;
    int s[8], d[8];
    if (W[WS_FLAG]) {
        #pragma unroll
        for (int k = 0; k < 8; k += 2) {
            int4 sv = *(const int4*)&idx[2 * (e0 + k)];
            int4 dv = *(const int4*)&idx[2 * (N_EDGES + e0 + k)];
            s[k] = sv.x; s[k + 1] = sv.z;
            d[k] = dv.x; d[k + 1] = dv.z;
        }
    } else {
        #pragma unroll
        for (int k = 0; k < 8; k += 4) {
            int4 sv = *(const int4*)&idx[e0 + k];
            int4 dv = *(const int4*)&idx[N_EDGES + e0 + k];
            s[k] = sv.x; s[k + 1] = sv.y; s[k + 2] = sv.z; s[k + 3] = sv.w;
            d[k] = dv.x; d[k + 1] = dv.y; d[k + 2] = dv.z; d[k + 3] = dv.w;
        }
    }
    int p[8];
    #pragma unroll
    for (int k = 0; k < 8; ++k) p[k] = atomicAdd(&W[WS_CURSOR + d[k]], 1);
    #pragma unroll
    for (int k = 0; k < 8; ++k) W[WS_SSRC + p[k]] = s[k];
}

// K4: one wave per node; lane = feature; fp16 interleaved gathers, fp32 accum
__global__ __launch_bounds__(256) void gather_reduce(const int* __restrict__ W,
                                                     float* __restrict__ out) {
    int wave = (int)((blockIdx.x * blockDim.x + threadIdx.x) >> 6);
    int lane = threadIdx.x & 63;
    if (wave >= N_NODES) return;
    int beg = W[WS_OFFS + wave];
    int end = W[WS_OFFS + wave + 1];
    const int* ssrc = W + WS_SSRC;
    const __half2* packed = (const __half2*)(W + WS_PACKED);

    float s0 = 0.f, s1 = 0.f, s2 = 0.f, s3 = 0.f;
    float p0 = 1.f, p1 = 1.f, p2 = 1.f, p3 = 1.f;
    int i = beg;
    for (; i + 3 < end; i += 4) {
        int a = ssrc[i], b = ssrc[i + 1], c = ssrc[i + 2], d = ssrc[i + 3];
        __half2 va = packed[a * D_FEAT + lane];
        __half2 vb = packed[b * D_FEAT + lane];
        __half2 vc = packed[c * D_FEAT + lane];
        __half2 vd = packed[d * D_FEAT + lane];
        float2 fa = __half22float2(va);
        float2 fb = __half22float2(vb);
        float2 fc = __half22float2(vc);
        float2 fd = __half22float2(vd);
        s0 += fa.x; s1 += fb.x; s2 += fc.x; s3 += fd.x;
        p0 *= fa.y; p1 *= fb.y; p2 *= fc.y; p3 *= fd.y;
    }
    for (; i < end; ++i) {
        int a = ssrc[i];
        float2 f = __half22float2(packed[a * D_FEAT + lane]);
        s0 += f.x;
        p0 *= f.y;
    }
    out[(long)wave * D_FEAT + lane] = (s0 + s1) + (s2 + s3);
    out[(long)N_NODES * D_FEAT + (long)wave * D_FEAT + lane] = (p0 * p1) * (p2 * p3);
}

// ---------------- fallback (atomic) path, used only if ws is too small ----------------
__device__ inline void atomicMulF32(float* addr, float val) {
    unsigned int* ua = (unsigned int*)addr;
    unsigned int old = __hip_atomic_load(ua, __ATOMIC_RELAXED, __HIP_MEMORY_SCOPE_AGENT);
    while (true) {
        unsigned int assumed = old;
        unsigned int desired = __float_as_uint(__uint_as_float(assumed) * val);
        old = atomicCAS(ua, assumed, desired);
        if (old == assumed) break;
    }
}

__global__ void fb_init(float* __restrict__ out, int* __restrict__ flag,
                        const int* __restrict__ idx) {
    const int n4 = (N_NODES * D_FEAT) / 4;
    int tid = blockIdx.x * blockDim.x + threadIdx.x;
    int stride = gridDim.x * blockDim.x;
    float4* o = (float4*)out;
    const float4 z = make_float4(0.f, 0.f, 0.f, 0.f);
    const float4 one = make_float4(1.f, 1.f, 1.f, 1.f);
    for (int i = tid; i < n4; i += stride) { o[i] = z; o[n4 + i] = one; }
    if (blockIdx.x == 0 && threadIdx.x == 0) detect_idx_layout(idx, flag);
}

__global__ void fb_scatter(const float* __restrict__ xs, const float* __restrict__ xp,
                           const int* __restrict__ idx, float* __restrict__ out,
                           const int* __restrict__ flag) {
    long tid = (long)blockIdx.x * blockDim.x + threadIdx.x;
    const long total = (long)N_EDGES * (D_FEAT / 4);
    if (tid >= total) return;
    int e = (int)(tid >> 4);
    int c = (int)(tid & 15);
    int src, dst;
    if (*flag) { src = idx[2 * e]; dst = idx[2 * (N_EDGES + e)]; }
    else       { src = idx[e];     dst = idx[N_EDGES + e]; }
    const float4 s = ((const float4*)(xs + (long)src * D_FEAT))[c];
    const float4 p = ((const float4*)(xp + (long)src * D_FEAT))[c];
    float* os = out + (long)dst * D_FEAT + c * 4;
    float* op = out + (long)N_NODES * D_FEAT + (long)dst * D_FEAT + c * 4;
    atomicAdd(os + 0, s.x); atomicAdd(os + 1, s.y);
    atomicAdd(os + 2, s.z); atomicAdd(os + 3, s.w);
    atomicMulF32(op + 0, p.x); atomicMulF32(op + 1, p.y);
    atomicMulF32(op + 2, p.z); atomicMulF32(op + 3, p.w);
}

extern "C" void kernel_launch(void* const* d_in, const int* in_sizes, int n_in,
                              void* d_out, int out_size, void* d_ws, size_t ws_size,
                              hipStream_t stream) {
    const float* x_sum  = (const float*)d_in[0];
    const float* x_prod = (const float*)d_in[1];
    const int*   eidx   = (const int*)d_in[2];
    float* out = (float*)d_out;
    int* W = (int*)d_ws;

    if (ws_size < (size_t)WS_INTS * sizeof(int)) {
        fb_init<<<1024, 256, 0, stream>>>(out, W, eidx);
        const long total = (long)N_EDGES * (D_FEAT / 4);
        int grid = (int)((total + 255) / 256);
        fb_scatter<<<grid, 256, 0, stream>>>(x_sum, x_prod, eidx, out, W);
        return;
    }

    init_cast<<<1024, 256, 0, stream>>>(W, eidx, x_sum, x_prod);
    hist_kernel<<<(N_EDGES / 8 + 255) / 256, 256, 0, stream>>>(eidx, W);
    scan_reduce<<<SCAN_B, 256, 0, stream>>>(W);
    scan_apply<<<SCAN_B, 256, 0, stream>>>(W);
    scatter_sort<<<(N_EDGES / 8 + 255) / 256, 256, 0, stream>>>(eidx, W);
    gather_reduce<<<(N_NODES + 3) / 4, 256, 0, stream>>>(W, out);
}